// Round 5
// baseline (189.281 us; speedup 1.0000x reference)
//
#include <hip/hip_runtime.h>
#include <hip/hip_bf16.h>

#define NB 32
#define NP 2048
#define NS 64
#define NK 128

// d_out layout (FLOAT32 elements)
#define MEAN_OFF 0
#define STD_OFF  1048576
#define XIDX_OFF 2097152
#define YIDX_OFF 2359296

#define GA_LD 576   // gA bf16 leading dim (515 padded)

typedef __attribute__((ext_vector_type(4)))  short s4;
typedef __attribute__((ext_vector_type(8)))  short short8;
typedef __attribute__((ext_vector_type(16))) float f32x16;

static __device__ __forceinline__ float leaky(float x){ return x >= 0.0f ? x : 0.2f * x; }

static __device__ __forceinline__ unsigned short bf16u(float v){
    __hip_bfloat16 h = __float2bfloat16(v);
    return *(unsigned short*)&h;
}

// strict IEEE fp32, no contraction — matches numpy/jax op order
static __device__ __forceinline__ float d2s(float ax,float ay,float az,float bx,float by,float bz){
    float dx = __fsub_rn(ax,bx), dy = __fsub_rn(ay,by), dz = __fsub_rn(az,bz);
    return __fadd_rn(__fadd_rn(__fmul_rn(dx,dx),__fmul_rn(dy,dy)),__fmul_rn(dz,dz));
}

// ---------------- FPS: one block per batch ----------------
__global__ __launch_bounds__(256) void fps_kernel(const float* __restrict__ pos,
                                                  float* __restrict__ centersWs)
{
    int b = blockIdx.x;
    int t = threadIdx.x;
    __shared__ float px[NP], py[NP], pz[NP];
    __shared__ float redv[4];
    __shared__ int   redi[4];
    __shared__ int   jsh;

    const float* pb = pos + (size_t)b * NP * 3;
    for (int n = t; n < NP; n += 256) {
        px[n] = pb[n*3+0]; py[n] = pb[n*3+1]; pz[n] = pb[n*3+2];
    }
    __syncthreads();

    float p0x = px[0], p0y = py[0], p0z = pz[0];
    float dl[8];
    #pragma unroll
    for (int q = 0; q < 8; q++) {
        int n = t + q*256;
        dl[q] = d2s(px[n],py[n],pz[n], p0x,p0y,p0z);
    }
    if (t == 0) {
        centersWs[(b*NS)*3+0] = p0x;
        centersWs[(b*NS)*3+1] = p0y;
        centersWs[(b*NS)*3+2] = p0z;
    }

    for (int s = 1; s < NS; s++) {
        float bv = -1.0f; int bi = 0;
        #pragma unroll
        for (int q = 0; q < 8; q++) {
            int n = t + q*256;
            if (dl[q] > bv) { bv = dl[q]; bi = n; }
        }
        #pragma unroll
        for (int m = 32; m > 0; m >>= 1) {
            float ov = __shfl_xor(bv, m);
            int   oi = __shfl_xor(bi, m);
            if (ov > bv || (ov == bv && oi < bi)) { bv = ov; bi = oi; }
        }
        int w = t >> 6;
        if ((t & 63) == 0) { redv[w] = bv; redi[w] = bi; }
        __syncthreads();
        if (t == 0) {
            float v = redv[0]; int i = redi[0];
            #pragma unroll
            for (int k = 1; k < 4; k++) {
                if (redv[k] > v || (redv[k] == v && redi[k] < i)) { v = redv[k]; i = redi[k]; }
            }
            jsh = i;
            centersWs[(b*NS+s)*3+0] = px[i];
            centersWs[(b*NS+s)*3+1] = py[i];
            centersWs[(b*NS+s)*3+2] = pz[i];
        }
        __syncthreads();
        int j = jsh;
        float cx = px[j], cy = py[j], cz = pz[j];
        #pragma unroll
        for (int q = 0; q < 8; q++) {
            int n = t + q*256;
            dl[q] = fminf(dl[q], d2s(px[n],py[n],pz[n], cx,cy,cz));
        }
    }
}

// ---------------- ball query: one wave per center ----------------
__global__ __launch_bounds__(64) void ball_kernel(const float* __restrict__ pos,
                                                  const float* __restrict__ centersWs,
                                                  int* __restrict__ nbrWs,
                                                  int* __restrict__ cntWs,
                                                  __hip_bfloat16* __restrict__ gAb,
                                                  float* __restrict__ out)
{
    int r = blockIdx.x;        // b*NS + s
    int b = r >> 6;
    int lane = threadIdx.x;
    float cx = centersWs[r*3+0], cy = centersWs[r*3+1], cz = centersWs[r*3+2];

    __shared__ int nb[NK];
    const float* pb = pos + (size_t)b * NP * 3;
    int total = 0;
    for (int base = 0; base < NP; base += 64) {
        int n = base + lane;
        float x = pb[n*3+0], y = pb[n*3+1], z = pb[n*3+2];
        float d2 = d2s(cx,cy,cz, x,y,z);
        bool in = d2 < 0.04f;
        unsigned long long m = __ballot(in);
        int before = __popcll(m & ((1ull << lane) - 1ull));
        int p = total + before;
        if (in && p < NK) nb[p] = n;
        total += (int)__popcll(m);
        if (total >= NK) break;
    }
    int cnt = total > NK ? NK : total;
    if (lane == 0) cntWs[r] = cnt;
    __syncthreads();

    #pragma unroll
    for (int k = lane; k < NK; k += 64) {
        bool valid = k < cnt;
        int nv = valid ? nb[k] : 0;
        nbrWs[r*NK + k] = nv;
        out[XIDX_OFF + r*NK + k] = valid ? (float)(nv + b*NP) : -1.0f;
        out[YIDX_OFF + r*NK + k] = valid ? (float)r : -1.0f;
    }
    // gA tail cols 512..575: center xyz then zeros
    {
        float v = 0.0f;
        if (lane == 0) v = cx; else if (lane == 1) v = cy; else if (lane == 2) v = cz;
        gAb[(size_t)r*GA_LD + 512 + lane] = __float2bfloat16(v);
    }
}

// ---------------- prep: bf16 transposed weights (linear) into ws ----------------
// W2T: [i=0..127][j=0..63]  = W2[j][i]               (16 KB)
// W3T: [c=0..511][i=0..127] = W3[i][c]               (128 KB)
// W4T: [n=0..511][k=0..575] = W4[k][n] (0 for k>=515) (576 KB)
// W5T: [n=0..1023][k=0..511]= W5[k][n]               (1 MB)
__global__ __launch_bounds__(256) void prep_kernel(const float* __restrict__ W2,
                                                   const float* __restrict__ W3,
                                                   const float* __restrict__ W4,
                                                   const float* __restrict__ W5,
                                                   __hip_bfloat16* __restrict__ W2T,
                                                   __hip_bfloat16* __restrict__ W3T,
                                                   __hip_bfloat16* __restrict__ W4T,
                                                   __hip_bfloat16* __restrict__ W5T)
{
    int g = blockIdx.x*256 + threadIdx.x;   // 0..131071
    if (g < 65536) {
        int c = g >> 7, i = g & 127;
        W3T[g] = __float2bfloat16(W3[(size_t)i*512 + c]);
    }
    if (g < 8192) {
        int i = g >> 6, j = g & 63;
        W2T[g] = __float2bfloat16(W2[(size_t)j*128 + i]);
    }
    for (int e = g; e < 512*GA_LD; e += 131072) {
        int n = e / GA_LD, k = e - n*GA_LD;
        float v = (k < 515) ? W4[(size_t)k*512 + n] : 0.0f;
        W4T[e] = __float2bfloat16(v);
    }
    for (int e = g; e < 1024*512; e += 131072) {
        int n = e >> 9, k = e & 511;
        W5T[e] = __float2bfloat16(W5[(size_t)k*1024 + n]);
    }
}

// ---------------- fused MLP(3->64->128->512) + masked max, MFMA bf16 v2 ----------------
// LDS: h1s [128k][64j] swz ((k&7)<<4)  @0      (16 KB)
//      h2s [128k][128i] swz ((k&15)<<4) @16384 (32 KB)
//      rel f32[128][4]                  @49152 (2 KB)   } aliased by
//      b2s f32[128]                     @51200 (0.5 KB) } red f32[8][128] @49152 (4 KB)
__global__ __launch_bounds__(256) void mlp_kernel(const float* __restrict__ pos,
                                                  const float* __restrict__ W1, const float* __restrict__ b1,
                                                  const float* __restrict__ b2, const float* __restrict__ b3,
                                                  const __hip_bfloat16* __restrict__ W2Tp,
                                                  const __hip_bfloat16* __restrict__ W3Tp,
                                                  const float* __restrict__ centersWs,
                                                  const int* __restrict__ nbrWs,
                                                  const int* __restrict__ cntWs,
                                                  __hip_bfloat16* __restrict__ gAb)
{
    __shared__ char smem[53248];
    char*  h1s = smem;
    char*  h2s = smem + 16384;
    float* rel = (float*)(smem + 49152);
    float* b2s = (float*)(smem + 51200);
    float* red = (float*)(smem + 49152);

    const short* W2T = (const short*)W2Tp;
    const short* W3T = (const short*)W3Tp;

    int r = blockIdx.x, b = r >> 6, tid = threadIdx.x;
    int l = tid & 63, w = tid >> 6;
    int l31 = l & 31;
    int hsel = l >> 5;               // 0/1
    int jsel8 = hsel * 8;            // element offset of lane's K-subgroup
    int colsel = hsel * 16;          // byte offset
    int cnt = cntWs[r];

    // layer-2 A-frags (W2^T) straight from global (L2-hot) — issue first, hide under everything
    int wi = w & 1, wk = w >> 1;
    short8 aW[2][4];
    #pragma unroll
    for (int rt = 0; rt < 2; rt++) {
        int ia = (2*wi + rt)*32 + l31;
        #pragma unroll
        for (int ks = 0; ks < 4; ks++)
            aW[rt][ks] = *(const short8*)(W2T + ia*64 + ks*16 + jsel8);
    }

    // stage rel + b2s
    if (tid < NK) {
        float cx = centersWs[r*3+0], cy = centersWs[r*3+1], cz = centersWs[r*3+2];
        int nv = nbrWs[r*NK + tid];
        const float* pp = pos + ((size_t)b*NP + nv)*3;
        rel[tid*4+0] = pp[0] - cx;
        rel[tid*4+1] = pp[1] - cy;
        rel[tid*4+2] = pp[2] - cz;
        rel[tid*4+3] = 0.0f;
        b2s[tid] = b2[tid];
    }
    __syncthreads();

    // ---- layer 1 (VALU): h1[k][j] = leaky(rel[k]·W1[:,j] + b1[j]), packed b64 stores
    {
        int jg = (tid & 15) * 4;
        float4 w0 = *(const float4*)&W1[jg];
        float4 w1 = *(const float4*)&W1[64 + jg];
        float4 w2 = *(const float4*)&W1[128 + jg];
        float4 bb = *(const float4*)&b1[jg];
        #pragma unroll
        for (int e = 0; e < 8; e++) {
            int k = (tid >> 4) + e*16;
            float4 r4 = *(const float4*)&rel[k*4];
            s4 pk;
            pk[0] = (short)bf16u(leaky(bb.x + r4.x*w0.x + r4.y*w1.x + r4.z*w2.x));
            pk[1] = (short)bf16u(leaky(bb.y + r4.x*w0.y + r4.y*w1.y + r4.z*w2.y));
            pk[2] = (short)bf16u(leaky(bb.z + r4.x*w0.z + r4.y*w1.z + r4.z*w2.z));
            pk[3] = (short)bf16u(leaky(bb.w + r4.x*w0.w + r4.y*w1.w + r4.z*w2.w));
            *(s4*)(h1s + k*128 + ((jg*2) ^ ((k&7)<<4))) = pk;
        }
    }
    __syncthreads();

    // ---- layer 2 (MFMA, swapped): D2[i][k] = sum_j W2^T[i][j] h1^T[j][k]
    {
        f32x16 acc[2][2];
        #pragma unroll
        for (int q = 0; q < 16; q++) { acc[0][0][q]=0.f; acc[0][1][q]=0.f; acc[1][0][q]=0.f; acc[1][1][q]=0.f; }
        int kc0 = (2*wk)*32 + l31, kc1 = kc0 + 32;
        #pragma unroll
        for (int ks = 0; ks < 4; ks++) {
            int bc = ks*32 + colsel;
            short8 bh0 = *(short8*)(h1s + kc0*128 + (bc ^ ((kc0&7)<<4)));
            short8 bh1 = *(short8*)(h1s + kc1*128 + (bc ^ ((kc1&7)<<4)));
            acc[0][0] = __builtin_amdgcn_mfma_f32_32x32x16_bf16(aW[0][ks], bh0, acc[0][0], 0, 0, 0);
            acc[0][1] = __builtin_amdgcn_mfma_f32_32x32x16_bf16(aW[0][ks], bh1, acc[0][1], 0, 0, 0);
            acc[1][0] = __builtin_amdgcn_mfma_f32_32x32x16_bf16(aW[1][ks], bh0, acc[1][0], 0, 0, 0);
            acc[1][1] = __builtin_amdgcn_mfma_f32_32x32x16_bf16(aW[1][ks], bh1, acc[1][1], 0, 0, 0);
        }
        // epilogue: bias(b2s) + leaky + pack 4 -> h2s[k][i]
        #pragma unroll
        for (int rt = 0; rt < 2; rt++) {
            int ibase = (2*wi + rt)*32 + 4*hsel;
            float4 bias[4];
            #pragma unroll
            for (int g = 0; g < 4; g++) bias[g] = *(const float4*)&b2s[ibase + g*8];
            #pragma unroll
            for (int ct = 0; ct < 2; ct++) {
                int k = (ct == 0) ? kc0 : kc1;
                #pragma unroll
                for (int g = 0; g < 4; g++) {
                    s4 pk;
                    pk[0] = (short)bf16u(leaky(acc[rt][ct][g*4+0] + bias[g].x));
                    pk[1] = (short)bf16u(leaky(acc[rt][ct][g*4+1] + bias[g].y));
                    pk[2] = (short)bf16u(leaky(acc[rt][ct][g*4+2] + bias[g].z));
                    pk[3] = (short)bf16u(leaky(acc[rt][ct][g*4+3] + bias[g].w));
                    *(s4*)(h2s + k*256 + (((ibase + g*8)*2) ^ ((k&15)<<4))) = pk;
                }
            }
        }
    }
    __syncthreads();

    // ---- layer 3 (MFMA) + masked max: D3[k][c], B-frags from global W3T (L2-hot)
    int wr = w & 1, wc = w >> 1;
    int k0 = (2*wr)*32 + l31, k1 = k0 + 32;
    int kb0 = 2*wr*32 + 4*hsel;
    for (int t = 0; t < 8; t++) {
        int cc = t >> 1, bt = t & 1;
        int c = cc*128 + (2*wc + bt)*32 + l31;
        short8 bw[8];
        #pragma unroll
        for (int ks = 0; ks < 8; ks++)
            bw[ks] = *(const short8*)(W3T + (size_t)c*128 + ks*16 + jsel8);
        f32x16 acc0, acc1;
        #pragma unroll
        for (int q = 0; q < 16; q++) { acc0[q] = 0.f; acc1[q] = 0.f; }
        #pragma unroll
        for (int ks = 0; ks < 8; ks++) {
            int bc = ks*32 + colsel;
            short8 a0 = *(short8*)(h2s + k0*256 + (bc ^ ((k0&15)<<4)));
            short8 a1 = *(short8*)(h2s + k1*256 + (bc ^ ((k1&15)<<4)));
            acc0 = __builtin_amdgcn_mfma_f32_32x32x16_bf16(a0, bw[ks], acc0, 0, 0, 0);
            acc1 = __builtin_amdgcn_mfma_f32_32x32x16_bf16(a1, bw[ks], acc1, 0, 0, 0);
        }
        float m = -INFINITY;
        #pragma unroll
        for (int reg = 0; reg < 16; reg++) {
            int kloc = (reg&3) + 8*(reg>>2);
            if (kb0 + kloc < cnt)      m = fmaxf(m, acc0[reg]);
            if (kb0 + 32 + kloc < cnt) m = fmaxf(m, acc1[reg]);
        }
        m = fmaxf(m, __shfl_xor(m, 32));
        if (l < 32)
            red[(cc*2 + wr)*128 + (2*wc + bt)*32 + l31] = m;
    }
    __syncthreads();

    // ---- final: combine wave partials, bias, leaky -> gAb
    #pragma unroll
    for (int e = 0; e < 2; e++) {
        int cidx = tid + e*256;
        int cc = cidx >> 7, cl = cidx & 127;
        float m = fmaxf(red[(cc*2+0)*128 + cl], red[(cc*2+1)*128 + cl]);
        gAb[(size_t)r*GA_LD + cidx] = __float2bfloat16(leaky(m + b3[cidx]));
    }
}

// ---------------- FC1 (MFMA): g2b = leaky(gAb[2048,576] @ W4T' + b4), N=512 ----------------
__global__ __launch_bounds__(256) void fc1_kernel(const __hip_bfloat16* __restrict__ gAb,
                                                  const __hip_bfloat16* __restrict__ W4T,
                                                  const float* __restrict__ b4,
                                                  __hip_bfloat16* __restrict__ g2b)
{
    __shared__ char smem[16384];
    char* As = smem;            // [64 rows][64 k] bf16, swz ((row&7)<<4)
    char* Bs = smem + 8192;     // [64 cols][64 k] bf16, swz

    int bx = blockIdx.x & 7;    // N tile (512/64)
    int by = blockIdx.x >> 3;   // M tile (2048/64)
    int tid = threadIdx.x;
    int l = tid & 63, w = tid >> 6;
    int wm = w & 1, wn = w >> 1;
    int colsel = (l >> 5) * 16;

    f32x16 acc;
    #pragma unroll
    for (int q = 0; q < 16; q++) acc[q] = 0.f;

    int ra = wm*32 + (l & 31);
    int rn = wn*32 + (l & 31);

    for (int kb = 0; kb < GA_LD; kb += 64) {
        #pragma unroll
        for (int it = 0; it < 2; it++) {
            int e = it*256 + tid;            // 0..511
            int row = e >> 3, seg = e & 7;
            short8 va = *(const short8*)(gAb + (size_t)(by*64 + row)*GA_LD + kb + seg*8);
            *(short8*)(As + row*128 + ((seg*16) ^ ((row&7)<<4))) = va;
            short8 vb = *(const short8*)(W4T + (size_t)(bx*64 + row)*GA_LD + kb + seg*8);
            *(short8*)(Bs + row*128 + ((seg*16) ^ ((row&7)<<4))) = vb;
        }
        __syncthreads();
        #pragma unroll
        for (int ks = 0; ks < 4; ks++) {
            int bc = ks*32 + colsel;
            short8 av = *(short8*)(As + ra*128 + (bc ^ ((ra&7)<<4)));
            short8 bv = *(short8*)(Bs + rn*128 + (bc ^ ((rn&7)<<4)));
            acc = __builtin_amdgcn_mfma_f32_32x32x16_bf16(av, bv, acc, 0, 0, 0);
        }
        __syncthreads();
    }

    int col = bx*64 + wn*32 + (l & 31);
    float bcol = b4[col];
    int rbase = by*64 + wm*32 + 4*(l>>5);
    #pragma unroll
    for (int reg = 0; reg < 16; reg++) {
        int row = rbase + (reg&3) + 8*(reg>>2);
        g2b[(size_t)row*512 + col] = __float2bfloat16(leaky(acc[reg] + bcol));
    }
}

// ---------------- FC2 (MFMA): out = g2b @ W5T' + b5; mean | std=exp(0.5 lv) ----------------
__global__ __launch_bounds__(256) void fc2_kernel(const __hip_bfloat16* __restrict__ g2b,
                                                  const __hip_bfloat16* __restrict__ W5T,
                                                  const float* __restrict__ b5,
                                                  float* __restrict__ out)
{
    __shared__ char smem[16384];
    char* As = smem;
    char* Bs = smem + 8192;

    int bx = blockIdx.x & 15;   // N tile (1024/64)
    int by = blockIdx.x >> 4;   // M tile (2048/64)
    int tid = threadIdx.x;
    int l = tid & 63, w = tid >> 6;
    int wm = w & 1, wn = w >> 1;
    int colsel = (l >> 5) * 16;

    f32x16 acc;
    #pragma unroll
    for (int q = 0; q < 16; q++) acc[q] = 0.f;

    int ra = wm*32 + (l & 31);
    int rn = wn*32 + (l & 31);

    for (int kb = 0; kb < 512; kb += 64) {
        #pragma unroll
        for (int it = 0; it < 2; it++) {
            int e = it*256 + tid;
            int row = e >> 3, seg = e & 7;
            short8 va = *(const short8*)(g2b + (size_t)(by*64 + row)*512 + kb + seg*8);
            *(short8*)(As + row*128 + ((seg*16) ^ ((row&7)<<4))) = va;
            short8 vb = *(const short8*)(W5T + (size_t)(bx*64 + row)*512 + kb + seg*8);
            *(short8*)(Bs + row*128 + ((seg*16) ^ ((row&7)<<4))) = vb;
        }
        __syncthreads();
        #pragma unroll
        for (int ks = 0; ks < 4; ks++) {
            int bc = ks*32 + colsel;
            short8 av = *(short8*)(As + ra*128 + (bc ^ ((ra&7)<<4)));
            short8 bv = *(short8*)(Bs + rn*128 + (bc ^ ((rn&7)<<4)));
            acc = __builtin_amdgcn_mfma_f32_32x32x16_bf16(av, bv, acc, 0, 0, 0);
        }
        __syncthreads();
    }

    int col = bx*64 + wn*32 + (l & 31);
    float bcol = b5[col];
    int rbase = by*64 + wm*32 + 4*(l>>5);
    #pragma unroll
    for (int reg = 0; reg < 16; reg++) {
        int row = rbase + (reg&3) + 8*(reg>>2);
        float v = acc[reg] + bcol;
        if (col < 512) {
            out[MEAN_OFF + (size_t)row*512 + col] = v;
        } else {
            out[STD_OFF + (size_t)row*512 + (col - 512)] = expf(0.5f*v);
        }
    }
}

extern "C" void kernel_launch(void* const* d_in, const int* in_sizes, int n_in,
                              void* d_out, int out_size, void* d_ws, size_t ws_size,
                              hipStream_t stream) {
    const float* pos = (const float*)d_in[0];
    const float* W1  = (const float*)d_in[2];
    const float* b1  = (const float*)d_in[3];
    const float* W2  = (const float*)d_in[4];
    const float* b2  = (const float*)d_in[5];
    const float* W3  = (const float*)d_in[6];
    const float* b3  = (const float*)d_in[7];
    const float* W4  = (const float*)d_in[8];
    const float* b4  = (const float*)d_in[9];
    const float* W5  = (const float*)d_in[10];
    const float* b5  = (const float*)d_in[11];
    float* out = (float*)d_out;

    char* ws = (char*)d_ws;
    float* centersWs = (float*)(ws);                          // 24576 B
    int*   cntWs     = (int*)(ws + 24576);                    // 8 KB
    int*   nbrWs     = (int*)(ws + 32768);                    // 1 MB
    __hip_bfloat16* gAb = (__hip_bfloat16*)(ws + 1081344);    // 2048*576*2 = 2359296
    __hip_bfloat16* g2b = (__hip_bfloat16*)(ws + 3440640);    // 2048*512*2 = 2097152
    __hip_bfloat16* W2T = (__hip_bfloat16*)(ws + 5537792);    // 16 KB
    __hip_bfloat16* W3T = (__hip_bfloat16*)(ws + 5554176);    // 128 KB
    __hip_bfloat16* W4T = (__hip_bfloat16*)(ws + 5685248);    // 576 KB
    __hip_bfloat16* W5T = (__hip_bfloat16*)(ws + 6275072);    // 1 MB -> ends 7323648

    hipLaunchKernelGGL(prep_kernel, dim3(512), dim3(256), 0, stream, W2, W3, W4, W5, W2T, W3T, W4T, W5T);
    hipLaunchKernelGGL(fps_kernel, dim3(NB), dim3(256), 0, stream, pos, centersWs);
    hipLaunchKernelGGL(ball_kernel, dim3(NB*NS), dim3(64), 0, stream, pos, centersWs, nbrWs, cntWs, gAb, out);
    hipLaunchKernelGGL(mlp_kernel, dim3(NB*NS), dim3(256), 0, stream,
                       pos, W1,b1, b2,b3, W2T, W3T, centersWs, nbrWs, cntWs, gAb);
    hipLaunchKernelGGL(fc1_kernel, dim3(256), dim3(256), 0, stream, gAb, W4T, b4, g2b);
    hipLaunchKernelGGL(fc2_kernel, dim3(512), dim3(256), 0, stream, g2b, W5T, b5, out);
}

// Round 6
// 172.669 us; speedup vs baseline: 1.0962x; 1.0962x over previous
//
#include <hip/hip_runtime.h>
#include <hip/hip_bf16.h>

#define NB 32
#define NP 2048
#define NS 64
#define NK 128

// d_out layout (FLOAT32 elements)
#define MEAN_OFF 0
#define STD_OFF  1048576
#define XIDX_OFF 2097152
#define YIDX_OFF 2359296

#define GA_LD 576   // gA bf16 leading dim (515 padded)

typedef __attribute__((ext_vector_type(4)))  short s4;
typedef __attribute__((ext_vector_type(8)))  short short8;
typedef __attribute__((ext_vector_type(16))) float f32x16;

static __device__ __forceinline__ float leaky(float x){ return x >= 0.0f ? x : 0.2f * x; }

static __device__ __forceinline__ unsigned short bf16u(float v){
    __hip_bfloat16 h = __float2bfloat16(v);
    return *(unsigned short*)&h;
}

// strict IEEE fp32, no contraction — matches numpy/jax op order
static __device__ __forceinline__ float d2s(float ax,float ay,float az,float bx,float by,float bz){
    float dx = __fsub_rn(ax,bx), dy = __fsub_rn(ay,by), dz = __fsub_rn(az,bz);
    return __fadd_rn(__fadd_rn(__fmul_rn(dx,dx),__fmul_rn(dy,dy)),__fmul_rn(dz,dz));
}

// ---------------- FPS: one block per batch ----------------
__global__ __launch_bounds__(256) void fps_kernel(const float* __restrict__ pos,
                                                  float* __restrict__ centersWs)
{
    int b = blockIdx.x;
    int t = threadIdx.x;
    __shared__ float px[NP], py[NP], pz[NP];
    __shared__ float redv[4];
    __shared__ int   redi[4];
    __shared__ int   jsh;

    const float* pb = pos + (size_t)b * NP * 3;
    for (int n = t; n < NP; n += 256) {
        px[n] = pb[n*3+0]; py[n] = pb[n*3+1]; pz[n] = pb[n*3+2];
    }
    __syncthreads();

    float p0x = px[0], p0y = py[0], p0z = pz[0];
    float dl[8];
    #pragma unroll
    for (int q = 0; q < 8; q++) {
        int n = t + q*256;
        dl[q] = d2s(px[n],py[n],pz[n], p0x,p0y,p0z);
    }
    if (t == 0) {
        centersWs[(b*NS)*3+0] = p0x;
        centersWs[(b*NS)*3+1] = p0y;
        centersWs[(b*NS)*3+2] = p0z;
    }

    for (int s = 1; s < NS; s++) {
        float bv = -1.0f; int bi = 0;
        #pragma unroll
        for (int q = 0; q < 8; q++) {
            int n = t + q*256;
            if (dl[q] > bv) { bv = dl[q]; bi = n; }
        }
        #pragma unroll
        for (int m = 32; m > 0; m >>= 1) {
            float ov = __shfl_xor(bv, m);
            int   oi = __shfl_xor(bi, m);
            if (ov > bv || (ov == bv && oi < bi)) { bv = ov; bi = oi; }
        }
        int w = t >> 6;
        if ((t & 63) == 0) { redv[w] = bv; redi[w] = bi; }
        __syncthreads();
        if (t == 0) {
            float v = redv[0]; int i = redi[0];
            #pragma unroll
            for (int k = 1; k < 4; k++) {
                if (redv[k] > v || (redv[k] == v && redi[k] < i)) { v = redv[k]; i = redi[k]; }
            }
            jsh = i;
            centersWs[(b*NS+s)*3+0] = px[i];
            centersWs[(b*NS+s)*3+1] = py[i];
            centersWs[(b*NS+s)*3+2] = pz[i];
        }
        __syncthreads();
        int j = jsh;
        float cx = px[j], cy = py[j], cz = pz[j];
        #pragma unroll
        for (int q = 0; q < 8; q++) {
            int n = t + q*256;
            dl[q] = fminf(dl[q], d2s(px[n],py[n],pz[n], cx,cy,cz));
        }
    }
}

// ---------------- ball query: one wave per center ----------------
__global__ __launch_bounds__(64) void ball_kernel(const float* __restrict__ pos,
                                                  const float* __restrict__ centersWs,
                                                  int* __restrict__ nbrWs,
                                                  int* __restrict__ cntWs,
                                                  __hip_bfloat16* __restrict__ gAb,
                                                  float* __restrict__ out)
{
    int r = blockIdx.x;        // b*NS + s
    int b = r >> 6;
    int lane = threadIdx.x;
    float cx = centersWs[r*3+0], cy = centersWs[r*3+1], cz = centersWs[r*3+2];

    __shared__ int nb[NK];
    const float* pb = pos + (size_t)b * NP * 3;
    int total = 0;
    for (int base = 0; base < NP; base += 64) {
        int n = base + lane;
        float x = pb[n*3+0], y = pb[n*3+1], z = pb[n*3+2];
        float d2 = d2s(cx,cy,cz, x,y,z);
        bool in = d2 < 0.04f;
        unsigned long long m = __ballot(in);
        int before = __popcll(m & ((1ull << lane) - 1ull));
        int p = total + before;
        if (in && p < NK) nb[p] = n;
        total += (int)__popcll(m);
        if (total >= NK) break;
    }
    int cnt = total > NK ? NK : total;
    if (lane == 0) cntWs[r] = cnt;
    __syncthreads();

    #pragma unroll
    for (int k = lane; k < NK; k += 64) {
        bool valid = k < cnt;
        int nv = valid ? nb[k] : 0;
        nbrWs[r*NK + k] = nv;
        out[XIDX_OFF + r*NK + k] = valid ? (float)(nv + b*NP) : -1.0f;
        out[YIDX_OFF + r*NK + k] = valid ? (float)r : -1.0f;
    }
    // gA tail cols 512..575: center xyz then zeros
    {
        float v = 0.0f;
        if (lane == 0) v = cx; else if (lane == 1) v = cy; else if (lane == 2) v = cz;
        gAb[(size_t)r*GA_LD + 512 + lane] = __float2bfloat16(v);
    }
}

// ---------------- prep ----------------
// W2T: [i=0..127][j=0..63] linear  = W2[j][i]                              (16 KB)
// W3T: swizzled image: byte(c,i) = c*256 + ((i*2) ^ ((c&15)<<4)) = W3[i][c] (128 KB)
// W4T: [n=0..511][k=0..575] = W4[k][n] (0 for k>=515)                      (576 KB)
// W5T: [n=0..1023][k=0..511]= W5[k][n]                                     (1 MB)
__global__ __launch_bounds__(256) void prep_kernel(const float* __restrict__ W2,
                                                   const float* __restrict__ W3,
                                                   const float* __restrict__ W4,
                                                   const float* __restrict__ W5,
                                                   __hip_bfloat16* __restrict__ W2T,
                                                   __hip_bfloat16* __restrict__ W3T,
                                                   __hip_bfloat16* __restrict__ W4T,
                                                   __hip_bfloat16* __restrict__ W5T)
{
    int g = blockIdx.x*256 + threadIdx.x;   // 0..131071
    if (g < 65536) {
        int c = g >> 7, i = g & 127;
        int byte = c*256 + ((i*2) ^ ((c&15)<<4));
        W3T[byte>>1] = __float2bfloat16(W3[(size_t)i*512 + c]);
    }
    if (g < 8192) {
        int i = g >> 6, j = g & 63;
        W2T[g] = __float2bfloat16(W2[(size_t)j*128 + i]);
    }
    for (int e = g; e < 512*GA_LD; e += 131072) {
        int n = e / GA_LD, k = e - n*GA_LD;
        float v = (k < 515) ? W4[(size_t)k*512 + n] : 0.0f;
        W4T[e] = __float2bfloat16(v);
    }
    for (int e = g; e < 1024*512; e += 131072) {
        int n = e >> 9, k = e & 511;
        W5T[e] = __float2bfloat16(W5[(size_t)k*1024 + n]);
    }
}

// ---------------- fused MLP(3->64->128->512) + masked max, MFMA bf16 v3 ----------------
// LDS: h1s @0      16 KB  (layer1 out [k][j] swz (k&7)<<4; later = W3 chunk buf1)
//      h2s @16384  32 KB  (layer2 out [k][i] swz (k&15)<<4)
//      w3s0 @49152 16 KB  (W3 chunk buf0)
//      red @65536  4 KB   f32[2][512]
//      rel @69632  2 KB   f32[128][4]
//      b2s @71680  0.5 KB
__global__ __launch_bounds__(256) void mlp_kernel(const float* __restrict__ pos,
                                                  const float* __restrict__ W1, const float* __restrict__ b1,
                                                  const float* __restrict__ b2, const float* __restrict__ b3,
                                                  const __hip_bfloat16* __restrict__ W2Tp,
                                                  const __hip_bfloat16* __restrict__ W3Tp,
                                                  const float* __restrict__ centersWs,
                                                  const int* __restrict__ nbrWs,
                                                  const int* __restrict__ cntWs,
                                                  __hip_bfloat16* __restrict__ gAb)
{
    __shared__ char smem[72192];
    char*  h1s = smem;
    char*  h2s = smem + 16384;
    char*  w3s0 = smem + 49152;
    float* red = (float*)(smem + 65536);
    float* rel = (float*)(smem + 69632);
    float* b2s = (float*)(smem + 71680);

    const short* W2T = (const short*)W2Tp;
    const char*  W3Tb = (const char*)W3Tp;

    int r = blockIdx.x, b = r >> 6, tid = threadIdx.x;
    int l = tid & 63, w = tid >> 6;
    int l31 = l & 31;
    int hsel = l >> 5;               // 0/1
    int jsel8 = hsel * 8;            // element offset of lane's K-subgroup
    int colsel = hsel * 16;          // byte offset
    int cnt = cntWs[r];

    // layer-2 A-frags (W2^T) straight from global (L2-hot) — issued FIRST (oldest vmem)
    int wi = w & 1, wk = w >> 1;
    short8 aW[2][4];
    #pragma unroll
    for (int rt = 0; rt < 2; rt++) {
        int ia = (2*wi + rt)*32 + l31;
        #pragma unroll
        for (int ks = 0; ks < 4; ks++)
            aW[rt][ks] = *(const short8*)(W2T + ia*64 + ks*16 + jsel8);
    }

    // stage rel + b2s
    if (tid < NK) {
        float cx = centersWs[r*3+0], cy = centersWs[r*3+1], cz = centersWs[r*3+2];
        int nv = nbrWs[r*NK + tid];
        const float* pp = pos + ((size_t)b*NP + nv)*3;
        rel[tid*4+0] = pp[0] - cx;
        rel[tid*4+1] = pp[1] - cy;
        rel[tid*4+2] = pp[2] - cz;
        rel[tid*4+3] = 0.0f;
        b2s[tid] = b2[tid];
    }

    // async-stage W3 chunk 0 -> w3s0 (16 KB, 4 DMA ops/thread, wave-uniform LDS base)
    {
        const char* src = W3Tb + 0*16384 + w*4096 + l*16;
        char* dst = w3s0 + w*4096;
        #pragma unroll
        for (int it = 0; it < 4; it++)
            __builtin_amdgcn_global_load_lds((const __attribute__((address_space(1))) void*)(src + it*1024),
                                             (__attribute__((address_space(3))) void*)(dst + it*1024), 16, 0, 0);
    }
    __syncthreads();

    // ---- layer 1 (VALU): h1[k][j] = leaky(rel[k]·W1[:,j] + b1[j]), packed b64 stores
    {
        int jg = (tid & 15) * 4;
        float4 w0 = *(const float4*)&W1[jg];
        float4 w1 = *(const float4*)&W1[64 + jg];
        float4 w2 = *(const float4*)&W1[128 + jg];
        float4 bb = *(const float4*)&b1[jg];
        #pragma unroll
        for (int e = 0; e < 8; e++) {
            int k = (tid >> 4) + e*16;
            float4 r4 = *(const float4*)&rel[k*4];
            s4 pk;
            pk[0] = (short)bf16u(leaky(bb.x + r4.x*w0.x + r4.y*w1.x + r4.z*w2.x));
            pk[1] = (short)bf16u(leaky(bb.y + r4.x*w0.y + r4.y*w1.y + r4.z*w2.y));
            pk[2] = (short)bf16u(leaky(bb.z + r4.x*w0.z + r4.y*w1.z + r4.z*w2.z));
            pk[3] = (short)bf16u(leaky(bb.w + r4.x*w0.w + r4.y*w1.w + r4.z*w2.w));
            *(s4*)(h1s + k*128 + ((jg*2) ^ ((k&7)<<4))) = pk;
        }
    }
    __syncthreads();

    // ---- layer 2 (MFMA, swapped): D2[i][k] = sum_j W2^T[i][j] h1^T[j][k]
    {
        f32x16 acc[2][2];
        #pragma unroll
        for (int q = 0; q < 16; q++) { acc[0][0][q]=0.f; acc[0][1][q]=0.f; acc[1][0][q]=0.f; acc[1][1][q]=0.f; }
        int kc0 = (2*wk)*32 + l31, kc1 = kc0 + 32;
        #pragma unroll
        for (int ks = 0; ks < 4; ks++) {
            int bc = ks*32 + colsel;
            short8 bh0 = *(short8*)(h1s + kc0*128 + (bc ^ ((kc0&7)<<4)));
            short8 bh1 = *(short8*)(h1s + kc1*128 + (bc ^ ((kc1&7)<<4)));
            acc[0][0] = __builtin_amdgcn_mfma_f32_32x32x16_bf16(aW[0][ks], bh0, acc[0][0], 0, 0, 0);
            acc[0][1] = __builtin_amdgcn_mfma_f32_32x32x16_bf16(aW[0][ks], bh1, acc[0][1], 0, 0, 0);
            acc[1][0] = __builtin_amdgcn_mfma_f32_32x32x16_bf16(aW[1][ks], bh0, acc[1][0], 0, 0, 0);
            acc[1][1] = __builtin_amdgcn_mfma_f32_32x32x16_bf16(aW[1][ks], bh1, acc[1][1], 0, 0, 0);
        }
        // epilogue: bias(b2s) + leaky + pack 4 -> h2s[k][i]
        #pragma unroll
        for (int rt = 0; rt < 2; rt++) {
            int ibase = (2*wi + rt)*32 + 4*hsel;
            float4 bias[4];
            #pragma unroll
            for (int g = 0; g < 4; g++) bias[g] = *(const float4*)&b2s[ibase + g*8];
            #pragma unroll
            for (int ct = 0; ct < 2; ct++) {
                int k = (ct == 0) ? kc0 : kc1;
                #pragma unroll
                for (int g = 0; g < 4; g++) {
                    s4 pk;
                    pk[0] = (short)bf16u(leaky(acc[rt][ct][g*4+0] + bias[g].x));
                    pk[1] = (short)bf16u(leaky(acc[rt][ct][g*4+1] + bias[g].y));
                    pk[2] = (short)bf16u(leaky(acc[rt][ct][g*4+2] + bias[g].z));
                    pk[3] = (short)bf16u(leaky(acc[rt][ct][g*4+3] + bias[g].w));
                    *(s4*)(h2s + k*256 + (((ibase + g*8)*2) ^ ((k&15)<<4))) = pk;
                }
            }
        }
    }
    __syncthreads();     // h2s ready, h1s free from here on

    // issue W3 chunk 1 -> h1s (buf1)
    {
        const char* src = W3Tb + 1*16384 + w*4096 + l*16;
        char* dst = h1s + w*4096;
        #pragma unroll
        for (int it = 0; it < 4; it++)
            __builtin_amdgcn_global_load_lds((const __attribute__((address_space(1))) void*)(src + it*1024),
                                             (__attribute__((address_space(3))) void*)(dst + it*1024), 16, 0, 0);
    }

    // ---- preload layer3 A-frags (h2) into registers: reused across all 8 chunks
    int wr = w & 1, wc = w >> 1;
    short8 a3[2][8];
    #pragma unroll
    for (int rt = 0; rt < 2; rt++) {
        int row = (2*wr + rt)*32 + l31;
        #pragma unroll
        for (int ks = 0; ks < 8; ks++) {
            int bc = ks*32 + colsel;
            a3[rt][ks] = *(short8*)(h2s + row*256 + (bc ^ ((row&15)<<4)));
        }
    }

    // ---- layer 3: 8 chunks of 64 cols, double-buffered DMA pipeline
    int crow = wc*32 + l31;                 // col within chunk
    int kb0 = 2*wr*32 + 4*hsel;
    #pragma unroll
    for (int t = 0; t < 8; t++) {
        if (t < 7) { asm volatile("s_waitcnt vmcnt(4)" ::: "memory"); }
        else       { asm volatile("s_waitcnt vmcnt(0)" ::: "memory"); }
        __builtin_amdgcn_sched_barrier(0);
        __builtin_amdgcn_s_barrier();
        __builtin_amdgcn_sched_barrier(0);

        char* buf = (t & 1) ? h1s : w3s0;
        f32x16 acc0, acc1;
        #pragma unroll
        for (int q = 0; q < 16; q++) { acc0[q] = 0.f; acc1[q] = 0.f; }
        #pragma unroll
        for (int ks = 0; ks < 8; ks++) {
            int bc = ks*32 + colsel;
            short8 bv = *(short8*)(buf + crow*256 + (bc ^ ((crow&15)<<4)));
            acc0 = __builtin_amdgcn_mfma_f32_32x32x16_bf16(a3[0][ks], bv, acc0, 0, 0, 0);
            acc1 = __builtin_amdgcn_mfma_f32_32x32x16_bf16(a3[1][ks], bv, acc1, 0, 0, 0);
        }
        float m = -INFINITY;
        #pragma unroll
        for (int reg = 0; reg < 16; reg++) {
            int kloc = (reg&3) + 8*(reg>>2);
            if (kb0 + kloc < cnt)      m = fmaxf(m, acc0[reg]);
            if (kb0 + 32 + kloc < cnt) m = fmaxf(m, acc1[reg]);
        }
        m = fmaxf(m, __shfl_xor(m, 32));
        if (l < 32) red[wr*512 + t*64 + crow] = m;

        __builtin_amdgcn_s_barrier();        // everyone done reading buf
        __builtin_amdgcn_sched_barrier(0);
        if (t + 2 < 8) {
            const char* src = W3Tb + (t+2)*16384 + w*4096 + l*16;
            char* dst = buf + w*4096;        // buf[t&1] is free now
            #pragma unroll
            for (int it = 0; it < 4; it++)
                __builtin_amdgcn_global_load_lds((const __attribute__((address_space(1))) void*)(src + it*1024),
                                                 (__attribute__((address_space(3))) void*)(dst + it*1024), 16, 0, 0);
        }
    }
    __syncthreads();

    // ---- final: combine wr partials, bias, leaky -> gAb
    #pragma unroll
    for (int e = 0; e < 2; e++) {
        int cidx = tid + e*256;
        float m = fmaxf(red[cidx], red[512 + cidx]);
        gAb[(size_t)r*GA_LD + cidx] = __float2bfloat16(leaky(m + b3[cidx]));
    }
}

// ---------------- FC1 (MFMA): g2b = leaky(gAb[2048,576] @ W4T' + b4), N=512 ----------------
__global__ __launch_bounds__(256) void fc1_kernel(const __hip_bfloat16* __restrict__ gAb,
                                                  const __hip_bfloat16* __restrict__ W4T,
                                                  const float* __restrict__ b4,
                                                  __hip_bfloat16* __restrict__ g2b)
{
    __shared__ char smem[16384];
    char* As = smem;            // [64 rows][64 k] bf16, swz ((row&7)<<4)
    char* Bs = smem + 8192;     // [64 cols][64 k] bf16, swz

    int bx = blockIdx.x & 7;    // N tile (512/64)
    int by = blockIdx.x >> 3;   // M tile (2048/64)
    int tid = threadIdx.x;
    int l = tid & 63, w = tid >> 6;
    int wm = w & 1, wn = w >> 1;
    int colsel = (l >> 5) * 16;

    f32x16 acc;
    #pragma unroll
    for (int q = 0; q < 16; q++) acc[q] = 0.f;

    int ra = wm*32 + (l & 31);
    int rn = wn*32 + (l & 31);

    for (int kb = 0; kb < GA_LD; kb += 64) {
        #pragma unroll
        for (int it = 0; it < 2; it++) {
            int e = it*256 + tid;            // 0..511
            int row = e >> 3, seg = e & 7;
            short8 va = *(const short8*)(gAb + (size_t)(by*64 + row)*GA_LD + kb + seg*8);
            *(short8*)(As + row*128 + ((seg*16) ^ ((row&7)<<4))) = va;
            short8 vb = *(const short8*)(W4T + (size_t)(bx*64 + row)*GA_LD + kb + seg*8);
            *(short8*)(Bs + row*128 + ((seg*16) ^ ((row&7)<<4))) = vb;
        }
        __syncthreads();
        #pragma unroll
        for (int ks = 0; ks < 4; ks++) {
            int bc = ks*32 + colsel;
            short8 av = *(short8*)(As + ra*128 + (bc ^ ((ra&7)<<4)));
            short8 bv = *(short8*)(Bs + rn*128 + (bc ^ ((rn&7)<<4)));
            acc = __builtin_amdgcn_mfma_f32_32x32x16_bf16(av, bv, acc, 0, 0, 0);
        }
        __syncthreads();
    }

    int col = bx*64 + wn*32 + (l & 31);
    float bcol = b4[col];
    int rbase = by*64 + wm*32 + 4*(l>>5);
    #pragma unroll
    for (int reg = 0; reg < 16; reg++) {
        int row = rbase + (reg&3) + 8*(reg>>2);
        g2b[(size_t)row*512 + col] = __float2bfloat16(leaky(acc[reg] + bcol));
    }
}

// ---------------- FC2 (MFMA): out = g2b @ W5T' + b5; mean | std=exp(0.5 lv) ----------------
__global__ __launch_bounds__(256) void fc2_kernel(const __hip_bfloat16* __restrict__ g2b,
                                                  const __hip_bfloat16* __restrict__ W5T,
                                                  const float* __restrict__ b5,
                                                  float* __restrict__ out)
{
    __shared__ char smem[16384];
    char* As = smem;
    char* Bs = smem + 8192;

    int bx = blockIdx.x & 15;   // N tile (1024/64)
    int by = blockIdx.x >> 4;   // M tile (2048/64)
    int tid = threadIdx.x;
    int l = tid & 63, w = tid >> 6;
    int wm = w & 1, wn = w >> 1;
    int colsel = (l >> 5) * 16;

    f32x16 acc;
    #pragma unroll
    for (int q = 0; q < 16; q++) acc[q] = 0.f;

    int ra = wm*32 + (l & 31);
    int rn = wn*32 + (l & 31);

    for (int kb = 0; kb < 512; kb += 64) {
        #pragma unroll
        for (int it = 0; it < 2; it++) {
            int e = it*256 + tid;
            int row = e >> 3, seg = e & 7;
            short8 va = *(const short8*)(g2b + (size_t)(by*64 + row)*512 + kb + seg*8);
            *(short8*)(As + row*128 + ((seg*16) ^ ((row&7)<<4))) = va;
            short8 vb = *(const short8*)(W5T + (size_t)(bx*64 + row)*512 + kb + seg*8);
            *(short8*)(Bs + row*128 + ((seg*16) ^ ((row&7)<<4))) = vb;
        }
        __syncthreads();
        #pragma unroll
        for (int ks = 0; ks < 4; ks++) {
            int bc = ks*32 + colsel;
            short8 av = *(short8*)(As + ra*128 + (bc ^ ((ra&7)<<4)));
            short8 bv = *(short8*)(Bs + rn*128 + (bc ^ ((rn&7)<<4)));
            acc = __builtin_amdgcn_mfma_f32_32x32x16_bf16(av, bv, acc, 0, 0, 0);
        }
        __syncthreads();
    }

    int col = bx*64 + wn*32 + (l & 31);
    float bcol = b5[col];
    int rbase = by*64 + wm*32 + 4*(l>>5);
    #pragma unroll
    for (int reg = 0; reg < 16; reg++) {
        int row = rbase + (reg&3) + 8*(reg>>2);
        float v = acc[reg] + bcol;
        if (col < 512) {
            out[MEAN_OFF + (size_t)row*512 + col] = v;
        } else {
            out[STD_OFF + (size_t)row*512 + (col - 512)] = expf(0.5f*v);
        }
    }
}

extern "C" void kernel_launch(void* const* d_in, const int* in_sizes, int n_in,
                              void* d_out, int out_size, void* d_ws, size_t ws_size,
                              hipStream_t stream) {
    const float* pos = (const float*)d_in[0];
    const float* W1  = (const float*)d_in[2];
    const float* b1  = (const float*)d_in[3];
    const float* W2  = (const float*)d_in[4];
    const float* b2  = (const float*)d_in[5];
    const float* W3  = (const float*)d_in[6];
    const float* b3  = (const float*)d_in[7];
    const float* W4  = (const float*)d_in[8];
    const float* b4  = (const float*)d_in[9];
    const float* W5  = (const float*)d_in[10];
    const float* b5  = (const float*)d_in[11];
    float* out = (float*)d_out;

    char* ws = (char*)d_ws;
    float* centersWs = (float*)(ws);                          // 24576 B
    int*   cntWs     = (int*)(ws + 24576);                    // 8 KB
    int*   nbrWs     = (int*)(ws + 32768);                    // 1 MB
    __hip_bfloat16* gAb = (__hip_bfloat16*)(ws + 1081344);    // 2048*576*2 = 2359296
    __hip_bfloat16* g2b = (__hip_bfloat16*)(ws + 3440640);    // 2048*512*2 = 2097152
    __hip_bfloat16* W2T = (__hip_bfloat16*)(ws + 5537792);    // 16 KB
    __hip_bfloat16* W3T = (__hip_bfloat16*)(ws + 5554176);    // 128 KB
    __hip_bfloat16* W4T = (__hip_bfloat16*)(ws + 5685248);    // 576 KB
    __hip_bfloat16* W5T = (__hip_bfloat16*)(ws + 6275072);    // 1 MB -> ends 7323648

    hipLaunchKernelGGL(prep_kernel, dim3(512), dim3(256), 0, stream, W2, W3, W4, W5, W2T, W3T, W4T, W5T);
    hipLaunchKernelGGL(fps_kernel, dim3(NB), dim3(256), 0, stream, pos, centersWs);
    hipLaunchKernelGGL(ball_kernel, dim3(NB*NS), dim3(64), 0, stream, pos, centersWs, nbrWs, cntWs, gAb, out);
    hipLaunchKernelGGL(mlp_kernel, dim3(NB*NS), dim3(256), 0, stream,
                       pos, W1,b1, b2,b3, W2T, W3T, centersWs, nbrWs, cntWs, gAb);
    hipLaunchKernelGGL(fc1_kernel, dim3(256), dim3(256), 0, stream, gAb, W4T, b4, g2b);
    hipLaunchKernelGGL(fc2_kernel, dim3(512), dim3(256), 0, stream, g2b, W5T, b5, out);
}

// Round 7
// 159.638 us; speedup vs baseline: 1.1857x; 1.0816x over previous
//
#include <hip/hip_runtime.h>
#include <hip/hip_bf16.h>

#define NB 32
#define NP 2048
#define NS 64
#define NK 128

// d_out layout (FLOAT32 elements)
#define MEAN_OFF 0
#define STD_OFF  1048576
#define XIDX_OFF 2097152
#define YIDX_OFF 2359296

#define GA_LD 576   // gA bf16 leading dim (515 padded)

typedef __attribute__((ext_vector_type(4)))  short s4;
typedef __attribute__((ext_vector_type(8)))  short short8;
typedef __attribute__((ext_vector_type(16))) float f32x16;

static __device__ __forceinline__ float leaky(float x){ return x >= 0.0f ? x : 0.2f * x; }

static __device__ __forceinline__ unsigned short bf16u(float v){
    __hip_bfloat16 h = __float2bfloat16(v);
    return *(unsigned short*)&h;
}

// strict IEEE fp32, no contraction — matches numpy/jax op order
static __device__ __forceinline__ float d2s(float ax,float ay,float az,float bx,float by,float bz){
    float dx = __fsub_rn(ax,bx), dy = __fsub_rn(ay,by), dz = __fsub_rn(az,bz);
    return __fadd_rn(__fadd_rn(__fmul_rn(dx,dx),__fmul_rn(dy,dy)),__fmul_rn(dz,dz));
}

// ---------------- FPS (blocks 0..31) + weight prep (blocks 32..543) ----------------
// W2T: [i=0..127][j=0..63] linear  = W2[j][i]                               (16 KB)
// W3T: swizzled image: byte(c,i) = c*256 + ((i*2) ^ ((c&15)<<4)) = W3[i][c] (128 KB)
// W4T: [n=0..511][k=0..575] = W4[k][n] (0 for k>=515)                       (576 KB)
// W5T: [n=0..1023][k=0..511]= W5[k][n]                                      (1 MB)
__global__ __launch_bounds__(256) void fps_prep_kernel(const float* __restrict__ pos,
                                                       float* __restrict__ centersWs,
                                                       const float* __restrict__ W2,
                                                       const float* __restrict__ W3,
                                                       const float* __restrict__ W4,
                                                       const float* __restrict__ W5,
                                                       __hip_bfloat16* __restrict__ W2T,
                                                       __hip_bfloat16* __restrict__ W3T,
                                                       __hip_bfloat16* __restrict__ W4T,
                                                       __hip_bfloat16* __restrict__ W5T)
{
    if (blockIdx.x >= NB) {
        // ---- prep path (512 blocks) ----
        int g = (blockIdx.x - NB)*256 + threadIdx.x;   // 0..131071
        if (g < 65536) {
            int c = g >> 7, i = g & 127;
            int byte = c*256 + ((i*2) ^ ((c&15)<<4));
            W3T[byte>>1] = __float2bfloat16(W3[(size_t)i*512 + c]);
        }
        if (g < 8192) {
            int i = g >> 6, j = g & 63;
            W2T[g] = __float2bfloat16(W2[(size_t)j*128 + i]);
        }
        for (int e = g; e < 512*GA_LD; e += 131072) {
            int n = e / GA_LD, k = e - n*GA_LD;
            float v = (k < 515) ? W4[(size_t)k*512 + n] : 0.0f;
            W4T[e] = __float2bfloat16(v);
        }
        for (int e = g; e < 1024*512; e += 131072) {
            int n = e >> 9, k = e & 511;
            W5T[e] = __float2bfloat16(W5[(size_t)k*1024 + n]);
        }
        return;
    }

    // ---- FPS path (blocks 0..31) ----
    int b = blockIdx.x;
    int t = threadIdx.x;
    __shared__ float px[NP], py[NP], pz[NP];
    __shared__ float redv[4];
    __shared__ int   redi[4];
    __shared__ int   jsh;

    const float* pb = pos + (size_t)b * NP * 3;
    for (int n = t; n < NP; n += 256) {
        px[n] = pb[n*3+0]; py[n] = pb[n*3+1]; pz[n] = pb[n*3+2];
    }
    __syncthreads();

    float p0x = px[0], p0y = py[0], p0z = pz[0];
    float dl[8];
    #pragma unroll
    for (int q = 0; q < 8; q++) {
        int n = t + q*256;
        dl[q] = d2s(px[n],py[n],pz[n], p0x,p0y,p0z);
    }
    if (t == 0) {
        centersWs[(b*NS)*3+0] = p0x;
        centersWs[(b*NS)*3+1] = p0y;
        centersWs[(b*NS)*3+2] = p0z;
    }

    for (int s = 1; s < NS; s++) {
        float bv = -1.0f; int bi = 0;
        #pragma unroll
        for (int q = 0; q < 8; q++) {
            int n = t + q*256;
            if (dl[q] > bv) { bv = dl[q]; bi = n; }
        }
        #pragma unroll
        for (int m = 32; m > 0; m >>= 1) {
            float ov = __shfl_xor(bv, m);
            int   oi = __shfl_xor(bi, m);
            if (ov > bv || (ov == bv && oi < bi)) { bv = ov; bi = oi; }
        }
        int w = t >> 6;
        if ((t & 63) == 0) { redv[w] = bv; redi[w] = bi; }
        __syncthreads();
        if (t == 0) {
            float v = redv[0]; int i = redi[0];
            #pragma unroll
            for (int k = 1; k < 4; k++) {
                if (redv[k] > v || (redv[k] == v && redi[k] < i)) { v = redv[k]; i = redi[k]; }
            }
            jsh = i;
            centersWs[(b*NS+s)*3+0] = px[i];
            centersWs[(b*NS+s)*3+1] = py[i];
            centersWs[(b*NS+s)*3+2] = pz[i];
        }
        __syncthreads();
        int j = jsh;
        float cx = px[j], cy = py[j], cz = pz[j];
        #pragma unroll
        for (int q = 0; q < 8; q++) {
            int n = t + q*256;
            dl[q] = fminf(dl[q], d2s(px[n],py[n],pz[n], cx,cy,cz));
        }
    }
}

// ---------------- fused ball query + MLP(3->64->128->512) + masked max ----------------
// LDS: h1s @0      16 KB  (layer1 out [k][j] swz (k&7)<<4; later W3 dbuf 2x8KB)
//      h2s @16384  32 KB  (layer2 out [k][i] swz (k&15)<<4)
//      relL @49152 2 KB   f32[128][4]  (aliases nbL int[4][128] during scan)
//      b2s @51200  0.5 KB
//      nb  @51712  0.5 KB int[128]
//      red @52224  0.5 KB f32[4][32]
//      cntW4 @52736 16 B
__global__ __launch_bounds__(256, 3) void ball_mlp_kernel(
    const float* __restrict__ pos,
    const float* __restrict__ W1, const float* __restrict__ b1,
    const float* __restrict__ b2, const float* __restrict__ b3,
    const __hip_bfloat16* __restrict__ W2Tp,
    const __hip_bfloat16* __restrict__ W3Tp,
    const float* __restrict__ centersWs,
    float* __restrict__ out,
    __hip_bfloat16* __restrict__ gAb)
{
    __shared__ char smem[52752];
    char*  h1s  = smem;
    char*  h2s  = smem + 16384;
    float* relL = (float*)(smem + 49152);
    int*   nbL  = (int*)(smem + 49152);
    float* b2s  = (float*)(smem + 51200);
    int*   nb   = (int*)(smem + 51712);
    float* red  = (float*)(smem + 52224);
    int*   cntW4= (int*)(smem + 52736);

    const short* W2T  = (const short*)W2Tp;
    const char*  W3Tb = (const char*)W3Tp;

    int r = blockIdx.x, b = r >> 6, tid = threadIdx.x;
    int l = tid & 63, w = tid >> 6;
    int l31 = l & 31;
    int hsel = l >> 5;
    int jsel8 = hsel * 8;
    int colsel = hsel * 16;

    float cx = centersWs[r*3+0], cy = centersWs[r*3+1], cz = centersWs[r*3+2];

    // layer-2 A-frags (W2^T) from global (L2-hot) — issued first
    int wi = w & 1, wk = w >> 1;
    short8 aW[2][4];
    #pragma unroll
    for (int rt = 0; rt < 2; rt++) {
        int ia = (2*wi + rt)*32 + l31;
        #pragma unroll
        for (int ks = 0; ks < 4; ks++)
            aW[rt][ks] = *(const short8*)(W2T + ia*64 + ks*16 + jsel8);
    }

    // ---- ball query: wave w scans points [w*512, w*512+512), ordered compaction
    const float* pb = pos + (size_t)b * NP * 3;
    {
        int myCnt = 0;
        #pragma unroll
        for (int c = 0; c < 8; c++) {
            int n = w*512 + c*64 + l;
            float x = pb[n*3+0], y = pb[n*3+1], z = pb[n*3+2];
            bool in = d2s(cx,cy,cz, x,y,z) < 0.04f;
            unsigned long long m = __ballot(in);
            int before = __popcll(m & ((1ull << l) - 1ull));
            int p = myCnt + before;
            if (in && p < NK) nbL[w*NK + p] = n;
            myCnt += (int)__popcll(m);
        }
        if (l == 0) cntW4[w] = myCnt;
    }
    __syncthreads();

    int c0 = cntW4[0], c1 = cntW4[1], c2 = cntW4[2], c3 = cntW4[3];
    int cnt = c0 + c1 + c2 + c3;
    cnt = cnt > NK ? NK : cnt;

    int nv = 0;
    if (tid < NK) {
        bool valid = tid < cnt;
        int seg = 0, off = 0;
        if (tid >= c0)           { seg = 1; off = c0; }
        if (tid >= c0 + c1)      { seg = 2; off = c0 + c1; }
        if (tid >= c0 + c1 + c2) { seg = 3; off = c0 + c1 + c2; }
        if (valid) nv = nbL[seg*NK + (tid - off)];
        out[XIDX_OFF + r*NK + tid] = valid ? (float)(nv + b*NP) : -1.0f;
        out[YIDX_OFF + r*NK + tid] = valid ? (float)r : -1.0f;
    }
    __syncthreads();          // nbL reads complete before relL overwrite

    if (tid < NK) {
        const float* pp = pb + (size_t)nv*3;
        relL[tid*4+0] = pp[0] - cx;
        relL[tid*4+1] = pp[1] - cy;
        relL[tid*4+2] = pp[2] - cz;
        relL[tid*4+3] = 0.0f;
        b2s[tid] = b2[tid];
    }
    __syncthreads();

    // ---- layer 1 (VALU): h1[k][j] = leaky(rel[k]·W1[:,j] + b1[j])
    {
        int jg = (tid & 15) * 4;
        float4 w0 = *(const float4*)&W1[jg];
        float4 w1 = *(const float4*)&W1[64 + jg];
        float4 w2 = *(const float4*)&W1[128 + jg];
        float4 bb = *(const float4*)&b1[jg];
        #pragma unroll
        for (int e = 0; e < 8; e++) {
            int k = (tid >> 4) + e*16;
            float4 r4 = *(const float4*)&relL[k*4];
            s4 pk;
            pk[0] = (short)bf16u(leaky(bb.x + r4.x*w0.x + r4.y*w1.x + r4.z*w2.x));
            pk[1] = (short)bf16u(leaky(bb.y + r4.x*w0.y + r4.y*w1.y + r4.z*w2.y));
            pk[2] = (short)bf16u(leaky(bb.z + r4.x*w0.z + r4.y*w1.z + r4.z*w2.z));
            pk[3] = (short)bf16u(leaky(bb.w + r4.x*w0.w + r4.y*w1.w + r4.z*w2.w));
            *(s4*)(h1s + k*128 + ((jg*2) ^ ((k&7)<<4))) = pk;
        }
    }
    __syncthreads();

    // ---- layer 2 (MFMA, swapped): D2[i][k] = sum_j W2^T[i][j] h1^T[j][k]
    {
        f32x16 acc[2][2];
        #pragma unroll
        for (int q = 0; q < 16; q++) { acc[0][0][q]=0.f; acc[0][1][q]=0.f; acc[1][0][q]=0.f; acc[1][1][q]=0.f; }
        int kc0 = (2*wk)*32 + l31, kc1 = kc0 + 32;
        #pragma unroll
        for (int ks = 0; ks < 4; ks++) {
            int bc = ks*32 + colsel;
            short8 bh0 = *(short8*)(h1s + kc0*128 + (bc ^ ((kc0&7)<<4)));
            short8 bh1 = *(short8*)(h1s + kc1*128 + (bc ^ ((kc1&7)<<4)));
            acc[0][0] = __builtin_amdgcn_mfma_f32_32x32x16_bf16(aW[0][ks], bh0, acc[0][0], 0, 0, 0);
            acc[0][1] = __builtin_amdgcn_mfma_f32_32x32x16_bf16(aW[0][ks], bh1, acc[0][1], 0, 0, 0);
            acc[1][0] = __builtin_amdgcn_mfma_f32_32x32x16_bf16(aW[1][ks], bh0, acc[1][0], 0, 0, 0);
            acc[1][1] = __builtin_amdgcn_mfma_f32_32x32x16_bf16(aW[1][ks], bh1, acc[1][1], 0, 0, 0);
        }
        #pragma unroll
        for (int rt = 0; rt < 2; rt++) {
            int ibase = (2*wi + rt)*32 + 4*hsel;
            float4 bias[4];
            #pragma unroll
            for (int g = 0; g < 4; g++) bias[g] = *(const float4*)&b2s[ibase + g*8];
            #pragma unroll
            for (int ct = 0; ct < 2; ct++) {
                int k = (ct == 0) ? kc0 : kc1;
                #pragma unroll
                for (int g = 0; g < 4; g++) {
                    s4 pk;
                    pk[0] = (short)bf16u(leaky(acc[rt][ct][g*4+0] + bias[g].x));
                    pk[1] = (short)bf16u(leaky(acc[rt][ct][g*4+1] + bias[g].y));
                    pk[2] = (short)bf16u(leaky(acc[rt][ct][g*4+2] + bias[g].z));
                    pk[3] = (short)bf16u(leaky(acc[rt][ct][g*4+3] + bias[g].w));
                    *(s4*)(h2s + k*256 + (((ibase + g*8)*2) ^ ((k&15)<<4))) = pk;
                }
            }
        }
    }
    __syncthreads();     // h2s ready, h1s free (becomes W3 double buffer)

    // issue W3 chunks 0,1 (8 KB each) into h1s halves
    {
        const char* s0 = W3Tb + 0*8192 + w*2048 + l*16;
        char* d0 = h1s + 0 + w*2048;
        __builtin_amdgcn_global_load_lds((const __attribute__((address_space(1))) void*)(s0),
                                         (__attribute__((address_space(3))) void*)(d0), 16, 0, 0);
        __builtin_amdgcn_global_load_lds((const __attribute__((address_space(1))) void*)(s0 + 1024),
                                         (__attribute__((address_space(3))) void*)(d0 + 1024), 16, 0, 0);
        const char* s1 = W3Tb + 1*8192 + w*2048 + l*16;
        char* d1 = h1s + 8192 + w*2048;
        __builtin_amdgcn_global_load_lds((const __attribute__((address_space(1))) void*)(s1),
                                         (__attribute__((address_space(3))) void*)(d1), 16, 0, 0);
        __builtin_amdgcn_global_load_lds((const __attribute__((address_space(1))) void*)(s1 + 1024),
                                         (__attribute__((address_space(3))) void*)(d1 + 1024), 16, 0, 0);
    }

    // preload layer3 A-frags: wave w owns k-quarter rows [w*32, w*32+32)
    short8 a3[8];
    {
        int row = w*32 + l31;
        #pragma unroll
        for (int ks = 0; ks < 8; ks++) {
            int bc = ks*32 + colsel;
            a3[ks] = *(short8*)(h2s + row*256 + (bc ^ ((row&15)<<4)));
        }
    }

    // ---- layer 3: 16 chunks of 32 cols, double-buffered DMA pipeline
    int kb0 = w*32 + 4*hsel;
    #pragma unroll
    for (int t = 0; t < 16; t++) {
        if (t < 15) { asm volatile("s_waitcnt vmcnt(2)" ::: "memory"); }
        else        { asm volatile("s_waitcnt vmcnt(0)" ::: "memory"); }
        __builtin_amdgcn_sched_barrier(0);
        __builtin_amdgcn_s_barrier();
        __builtin_amdgcn_sched_barrier(0);

        char* buf = h1s + (t & 1)*8192;
        f32x16 acc;
        #pragma unroll
        for (int q = 0; q < 16; q++) acc[q] = 0.f;
        #pragma unroll
        for (int ks = 0; ks < 8; ks++) {
            int bc = ks*32 + colsel;
            short8 bv = *(short8*)(buf + l31*256 + (bc ^ ((l31&15)<<4)));
            acc = __builtin_amdgcn_mfma_f32_32x32x16_bf16(a3[ks], bv, acc, 0, 0, 0);
        }
        float m = -INFINITY;
        #pragma unroll
        for (int reg = 0; reg < 16; reg++) {
            int kloc = (reg&3) + 8*(reg>>2);
            if (kb0 + kloc < cnt) m = fmaxf(m, acc[reg]);
        }
        m = fmaxf(m, __shfl_xor(m, 32));
        if (l < 32) red[w*32 + l31] = m;

        __builtin_amdgcn_s_barrier();
        __builtin_amdgcn_sched_barrier(0);
        if (tid < 32) {
            float m4 = fmaxf(fmaxf(red[tid], red[32 + tid]), fmaxf(red[64 + tid], red[96 + tid]));
            float bc3 = b3[t*32 + tid];
            gAb[(size_t)r*GA_LD + t*32 + tid] = __float2bfloat16(leaky(m4 + bc3));
        }
        __builtin_amdgcn_sched_barrier(0);
        if (t + 2 < 16) {
            const char* src = W3Tb + (t+2)*8192 + w*2048 + l*16;
            char* dst = buf + w*2048;
            __builtin_amdgcn_global_load_lds((const __attribute__((address_space(1))) void*)(src),
                                             (__attribute__((address_space(3))) void*)(dst), 16, 0, 0);
            __builtin_amdgcn_global_load_lds((const __attribute__((address_space(1))) void*)(src + 1024),
                                             (__attribute__((address_space(3))) void*)(dst + 1024), 16, 0, 0);
        }
    }

    // tail cols 512..575: center xyz then zeros
    if (tid < 64) {
        float v = 0.0f;
        if (tid == 0) v = cx; else if (tid == 1) v = cy; else if (tid == 2) v = cz;
        gAb[(size_t)r*GA_LD + 512 + tid] = __float2bfloat16(v);
    }
}

// ---------------- FC1 (MFMA): g2b = leaky(gAb[2048,576] @ W4T' + b4), N=512 ----------------
__global__ __launch_bounds__(256) void fc1_kernel(const __hip_bfloat16* __restrict__ gAb,
                                                  const __hip_bfloat16* __restrict__ W4T,
                                                  const float* __restrict__ b4,
                                                  __hip_bfloat16* __restrict__ g2b)
{
    __shared__ char smem[16384];
    char* As = smem;            // [64 rows][64 k] bf16, swz ((row&7)<<4)
    char* Bs = smem + 8192;     // [64 cols][64 k] bf16, swz

    int bx = blockIdx.x & 7;    // N tile (512/64)
    int by = blockIdx.x >> 3;   // M tile (2048/64)
    int tid = threadIdx.x;
    int l = tid & 63, w = tid >> 6;
    int wm = w & 1, wn = w >> 1;
    int colsel = (l >> 5) * 16;

    f32x16 acc;
    #pragma unroll
    for (int q = 0; q < 16; q++) acc[q] = 0.f;

    int ra = wm*32 + (l & 31);
    int rn = wn*32 + (l & 31);

    for (int kb = 0; kb < GA_LD; kb += 64) {
        #pragma unroll
        for (int it = 0; it < 2; it++) {
            int e = it*256 + tid;            // 0..511
            int row = e >> 3, seg = e & 7;
            short8 va = *(const short8*)(gAb + (size_t)(by*64 + row)*GA_LD + kb + seg*8);
            *(short8*)(As + row*128 + ((seg*16) ^ ((row&7)<<4))) = va;
            short8 vb = *(const short8*)(W4T + (size_t)(bx*64 + row)*GA_LD + kb + seg*8);
            *(short8*)(Bs + row*128 + ((seg*16) ^ ((row&7)<<4))) = vb;
        }
        __syncthreads();
        #pragma unroll
        for (int ks = 0; ks < 4; ks++) {
            int bc = ks*32 + colsel;
            short8 av = *(short8*)(As + ra*128 + (bc ^ ((ra&7)<<4)));
            short8 bv = *(short8*)(Bs + rn*128 + (bc ^ ((rn&7)<<4)));
            acc = __builtin_amdgcn_mfma_f32_32x32x16_bf16(av, bv, acc, 0, 0, 0);
        }
        __syncthreads();
    }

    int col = bx*64 + wn*32 + (l & 31);
    float bcol = b4[col];
    int rbase = by*64 + wm*32 + 4*(l>>5);
    #pragma unroll
    for (int reg = 0; reg < 16; reg++) {
        int row = rbase + (reg&3) + 8*(reg>>2);
        g2b[(size_t)row*512 + col] = __float2bfloat16(leaky(acc[reg] + bcol));
    }
}

// ---------------- FC2 (MFMA): out = g2b @ W5T' + b5; mean | std=exp(0.5 lv) ----------------
__global__ __launch_bounds__(256) void fc2_kernel(const __hip_bfloat16* __restrict__ g2b,
                                                  const __hip_bfloat16* __restrict__ W5T,
                                                  const float* __restrict__ b5,
                                                  float* __restrict__ out)
{
    __shared__ char smem[16384];
    char* As = smem;
    char* Bs = smem + 8192;

    int bx = blockIdx.x & 15;   // N tile (1024/64)
    int by = blockIdx.x >> 4;   // M tile (2048/64)
    int tid = threadIdx.x;
    int l = tid & 63, w = tid >> 6;
    int wm = w & 1, wn = w >> 1;
    int colsel = (l >> 5) * 16;

    f32x16 acc;
    #pragma unroll
    for (int q = 0; q < 16; q++) acc[q] = 0.f;

    int ra = wm*32 + (l & 31);
    int rn = wn*32 + (l & 31);

    for (int kb = 0; kb < 512; kb += 64) {
        #pragma unroll
        for (int it = 0; it < 2; it++) {
            int e = it*256 + tid;
            int row = e >> 3, seg = e & 7;
            short8 va = *(const short8*)(g2b + (size_t)(by*64 + row)*512 + kb + seg*8);
            *(short8*)(As + row*128 + ((seg*16) ^ ((row&7)<<4))) = va;
            short8 vb = *(const short8*)(W5T + (size_t)(bx*64 + row)*512 + kb + seg*8);
            *(short8*)(Bs + row*128 + ((seg*16) ^ ((row&7)<<4))) = vb;
        }
        __syncthreads();
        #pragma unroll
        for (int ks = 0; ks < 4; ks++) {
            int bc = ks*32 + colsel;
            short8 av = *(short8*)(As + ra*128 + (bc ^ ((ra&7)<<4)));
            short8 bv = *(short8*)(Bs + rn*128 + (bc ^ ((rn&7)<<4)));
            acc = __builtin_amdgcn_mfma_f32_32x32x16_bf16(av, bv, acc, 0, 0, 0);
        }
        __syncthreads();
    }

    int col = bx*64 + wn*32 + (l & 31);
    float bcol = b5[col];
    int rbase = by*64 + wm*32 + 4*(l>>5);
    #pragma unroll
    for (int reg = 0; reg < 16; reg++) {
        int row = rbase + (reg&3) + 8*(reg>>2);
        float v = acc[reg] + bcol;
        if (col < 512) {
            out[MEAN_OFF + (size_t)row*512 + col] = v;
        } else {
            out[STD_OFF + (size_t)row*512 + (col - 512)] = expf(0.5f*v);
        }
    }
}

extern "C" void kernel_launch(void* const* d_in, const int* in_sizes, int n_in,
                              void* d_out, int out_size, void* d_ws, size_t ws_size,
                              hipStream_t stream) {
    const float* pos = (const float*)d_in[0];
    const float* W1  = (const float*)d_in[2];
    const float* b1  = (const float*)d_in[3];
    const float* W2  = (const float*)d_in[4];
    const float* b2  = (const float*)d_in[5];
    const float* W3  = (const float*)d_in[6];
    const float* b3  = (const float*)d_in[7];
    const float* W4  = (const float*)d_in[8];
    const float* b4  = (const float*)d_in[9];
    const float* W5  = (const float*)d_in[10];
    const float* b5  = (const float*)d_in[11];
    float* out = (float*)d_out;

    char* ws = (char*)d_ws;
    float* centersWs = (float*)(ws);                          // 24576 B
    __hip_bfloat16* gAb = (__hip_bfloat16*)(ws + 1081344);    // 2048*576*2 = 2359296
    __hip_bfloat16* g2b = (__hip_bfloat16*)(ws + 3440640);    // 2048*512*2 = 2097152
    __hip_bfloat16* W2T = (__hip_bfloat16*)(ws + 5537792);    // 16 KB
    __hip_bfloat16* W3T = (__hip_bfloat16*)(ws + 5554176);    // 128 KB
    __hip_bfloat16* W4T = (__hip_bfloat16*)(ws + 5685248);    // 576 KB
    __hip_bfloat16* W5T = (__hip_bfloat16*)(ws + 6275072);    // 1 MB -> ends 7323648

    hipLaunchKernelGGL(fps_prep_kernel, dim3(NB + 512), dim3(256), 0, stream,
                       pos, centersWs, W2, W3, W4, W5, W2T, W3T, W4T, W5T);
    hipLaunchKernelGGL(ball_mlp_kernel, dim3(NB*NS), dim3(256), 0, stream,
                       pos, W1,b1, b2,b3, W2T, W3T, centersWs, out, gAb);
    hipLaunchKernelGGL(fc1_kernel, dim3(256), dim3(256), 0, stream, gAb, W4T, b4, g2b);
    hipLaunchKernelGGL(fc2_kernel, dim3(512), dim3(256), 0, stream, g2b, W5T, b5, out);
}